// Round 4
// baseline (542.312 us; speedup 1.0000x reference)
//
#include <hip/hip_runtime.h>
#include <hip/hip_bf16.h>

// CentroidsFlowAD: out[row] = sqrt(max(||e||^2 + min_col(||c||^2 - 2 e.c), 0))
// rows = 32*3136 = 100352, cols = 2048 centroids, K = 1024.
//
// Fast path (needs ~204 MiB ws):
//   1. rowsq_bf16 on centroids  -> cbf (bf16) + csq
//   2. rowsq_bf16 on embeds     -> ebf (bf16) + esq
//   3. gemm_min_w128: 128x256 block, 4 waves (each 128x64, acc 8x4), BK=32,
//      TRIPLE-buffered LDS (72 KiB) -> 2 blocks/CU, one barrier per K-step,
//      counted vmcnt(6) (never 0 mid-loop). Phase: vmcnt(6) | barrier |
//      12 ds_read_b128 | stage(t+2) | 32 MFMA. Discipline: vmcnt wait
//      BEFORE barrier; staged-data reads AFTER barrier (R3's race fixed).
//      Swizzle sl^((row>>1)&3) for 64B rows (2-way residual, free).
//   4. final_min8: 8-way min + sqrt
// Fallback: round-1 fused kernel (proven).

typedef __bf16 bf16x8 __attribute__((ext_vector_type(8)));
typedef __bf16 bf16x4 __attribute__((ext_vector_type(4)));
typedef float f32x4 __attribute__((ext_vector_type(4)));

#define N_ROWS 100352
#define M_CENT 2048
#define D_K 1024

// fast-path geometry
#define BM3 128
#define BN3 256
#define BK3 32
#define NSTEP3 (D_K / BK3)             // 32 K-steps
#define NCT3 (M_CENT / BN3)            // 8 col tiles
#define NBLK3 ((N_ROWS / BM3) * NCT3)  // 6272
#define BPX3 (NBLK3 / 8)               // 784 blocks per XCD
#define BUFSZ 24576                    // A[128][32] 8K | B[256][32] 16K

// fallback geometry (round-1, unchanged)
#define TM 128
#define TN 128
#define BK 64
#define NT_TILES (M_CENT / TN)  // 16
#define KT_STEPS (D_K / BK)     // 16

#define AS1 __attribute__((address_space(1)))
#define AS3 __attribute__((address_space(3)))

#define WAITVM(N) asm volatile("s_waitcnt vmcnt(" #N ")" ::: "memory")
#define FENCE asm volatile("" ::: "memory")

// ---- prep: fp32 [rows][1024] -> bf16 row-major + per-row squared norm ----
__global__ __launch_bounds__(256) void rowsq_bf16(const float* __restrict__ src,
                                                  __bf16* __restrict__ dst,
                                                  float* __restrict__ sq) {
  const int m = blockIdx.x;   // row
  const int t = threadIdx.x;  // 256 threads * 4 floats = 1024
  const float4 v = *reinterpret_cast<const float4*>(src + (size_t)m * D_K + t * 4);
  bf16x4 o = {(__bf16)v.x, (__bf16)v.y, (__bf16)v.z, (__bf16)v.w};
  *reinterpret_cast<bf16x4*>(dst + (size_t)m * D_K + t * 4) = o;
  float ss = v.x * v.x + v.y * v.y + v.z * v.z + v.w * v.w;
  ss += __shfl_xor(ss, 1);
  ss += __shfl_xor(ss, 2);
  ss += __shfl_xor(ss, 4);
  ss += __shfl_xor(ss, 8);
  ss += __shfl_xor(ss, 16);
  ss += __shfl_xor(ss, 32);
  __shared__ float ws4[4];
  const int w = t >> 6, l = t & 63;
  if (l == 0) ws4[w] = ss;
  __syncthreads();
  if (t == 0) sq[m] = ws4[0] + ws4[1] + ws4[2] + ws4[3];
}

// ---- fast path: 128x256 block, wave tile 128x64, BK=32, triple buffer ----
// LDS buffer: A rows 0..127 at [0,8K), B rows(cols) 0..255 at [8K,24K).
// Row = 64 B = 4 x 16B slots; slot sl stores global k-group (sl^((row>>1)&3)).
// Staging: 6 global_load_lds w=16 per thread per K-step (A:2, B:4), FIFO.
// Pipeline (phase t2, buf = t2%3):
//   WAITVM(6)   -- my stage(t2) landed (stage(t2+1) in flight)
//   s_barrier   -- ALL waves' stage(t2) landed  (read-safety)
//   ds_read 12 frags from buf[t2%3]
//   stage(t2+2) into buf[(t2+2)%3]  -- overwrites buf read at t2-1; safe:
//                   this barrier ordered after all waves' t2-1 reads.
//   32 MFMA (setprio)
__global__ __launch_bounds__(256, 2) void gemm_min_w128(const __bf16* __restrict__ ebf,
                                                        const __bf16* __restrict__ cbf,
                                                        const float* __restrict__ csq,
                                                        float* __restrict__ pmin) {
  __shared__ __align__(16) char lds[3 * BUFSZ];
  __shared__ float rowmin4[4][BM3];

  const int t = threadIdx.x;
  const int wc = t >> 6;  // wave = column strip 0..3
  const int l = t & 63;
  const int g = l >> 4, lr = l & 15;

  // XCD swizzle: nwg = 6272 = 8*784; XCD k owns swz in [784k, 784k+784)
  // = rp in [98k, 98k+98) x all 8 ct. B (4 MB) L2-resident per XCD;
  // A panel (256 KB) reused by 8 consecutive blocks -> L2-hot.
  const int b = blockIdx.x;
  const int swz = (b & 7) * BPX3 + (b >> 3);
  const int rp = swz >> 3, ct = swz & 7;
  const long row0 = (long)rp * BM3;
  const int col0 = ct * BN3;

  // staging bases: thread t covers slot S = i*256 + t -> row = S>>2 (i
  // advances row by 64: (row>>1)&3 invariant), sl = S&3 = t&3.
  const int srow = t >> 2, ssl = t & 3;
  const int sswz = (ssl ^ ((srow >> 1) & 3)) << 3;  // element offset of 16B grp
  const __bf16* srcA0 = ebf + (row0 + srow) * (size_t)D_K + sswz;
  const __bf16* srcB0 = cbf + (size_t)(col0 + srow) * D_K + sswz;
  const int dst0 = t * 16;

  f32x4 acc[8][4];
#pragma unroll
  for (int m = 0; m < 8; ++m)
#pragma unroll
    for (int n = 0; n < 4; ++n) acc[m][n] = (f32x4){0.f, 0.f, 0.f, 0.f};

  // loop-invariant swizzled read offsets
  int offA[8], offB[4];
#pragma unroll
  for (int m = 0; m < 8; ++m) {
    const int row = m * 16 + lr;
    offA[m] = row * 64 + ((g ^ ((row >> 1) & 3)) << 4);
  }
#pragma unroll
  for (int n = 0; n < 4; ++n) {
    const int col = wc * 64 + n * 16 + lr;
    offB[n] = 8192 + col * 64 + ((g ^ ((col >> 1) & 3)) << 4);
  }

  bf16x8 af[8], bfr[4];

  auto stage = [&](int t2, int buf) {
    const size_t ko = (size_t)t2 * BK3;
    char* base = lds + buf * BUFSZ;
#pragma unroll
    for (int i = 0; i < 2; ++i)
      __builtin_amdgcn_global_load_lds(
          (const AS1 unsigned int*)(const void*)(srcA0 + (size_t)i * 64 * D_K + ko),
          (AS3 unsigned int*)(void*)(base + i * 4096 + dst0), 16, 0, 0);
#pragma unroll
    for (int i = 0; i < 4; ++i)
      __builtin_amdgcn_global_load_lds(
          (const AS1 unsigned int*)(const void*)(srcB0 + (size_t)i * 64 * D_K + ko),
          (AS3 unsigned int*)(void*)(base + 8192 + i * 4096 + dst0), 16, 0, 0);
  };

  auto readfrags = [&](int buf) {
    const char* base = lds + buf * BUFSZ;
#pragma unroll
    for (int m = 0; m < 8; ++m) af[m] = *reinterpret_cast<const bf16x8*>(base + offA[m]);
#pragma unroll
    for (int n = 0; n < 4; ++n) bfr[n] = *reinterpret_cast<const bf16x8*>(base + offB[n]);
  };

  auto domfma = [&]() {
    __builtin_amdgcn_s_setprio(1);
#pragma unroll
    for (int m = 0; m < 8; ++m)
#pragma unroll
      for (int n = 0; n < 4; ++n)
        acc[m][n] =
            __builtin_amdgcn_mfma_f32_16x16x32_bf16(af[m], bfr[n], acc[m][n], 0, 0, 0);
    __builtin_amdgcn_s_setprio(0);
  };

  // one pipeline phase: wait -> barrier -> read -> stage(next+2) -> mfma
  auto phase = [&](int t2, int rbuf, int sbuf, bool do_stage) {
    if (do_stage) {
      WAITVM(6);
    } else {
      // tail phases: t2==30 -> stage(31) still allowed in flight (6);
      // t2==31 -> full drain.
      if (t2 == NSTEP3 - 2) {
        WAITVM(6);
      } else {
        WAITVM(0);
      }
    }
    FENCE;
    __builtin_amdgcn_s_barrier();
    FENCE;
    readfrags(rbuf);
    if (do_stage) stage(t2 + 2, sbuf);
    domfma();
  };

  // prologue: two K-steps in flight (12 loads)
  stage(0, 0);
  stage(1, 1);

  // 30 interior phases, unrolled x3 for static buffer indices
  for (int kt = 0; kt < NSTEP3 - 2; kt += 3) {
    phase(kt + 0, 0, 2, true);   // read buf0, stage(kt+2)->buf2
    phase(kt + 1, 1, 0, true);   // read buf1, stage(kt+3)->buf0
    phase(kt + 2, 2, 1, true);   // read buf2, stage(kt+4)->buf1
  }
  phase(NSTEP3 - 2, 0, 0, false);  // t2=30: read buf0
  phase(NSTEP3 - 1, 1, 0, false);  // t2=31: read buf1 (vmcnt 0)

  // --- partial min over this block's 256 cols: val = ||c||^2 - 2*dot ---
  float runmin[8][4];
#pragma unroll
  for (int m = 0; m < 8; ++m)
#pragma unroll
    for (int r = 0; r < 4; ++r) runmin[m][r] = 3.0e38f;
#pragma unroll
  for (int n = 0; n < 4; ++n) {
    const float cs = csq[col0 + wc * 64 + n * 16 + lr];
#pragma unroll
    for (int m = 0; m < 8; ++m)
#pragma unroll
      for (int r = 0; r < 4; ++r)
        runmin[m][r] = fminf(runmin[m][r], cs - 2.0f * acc[m][n][r]);
  }
#pragma unroll
  for (int m = 0; m < 8; ++m)
#pragma unroll
    for (int r = 0; r < 4; ++r) {
      float v = runmin[m][r];
      v = fminf(v, __shfl_xor(v, 1));
      v = fminf(v, __shfl_xor(v, 2));
      v = fminf(v, __shfl_xor(v, 4));
      v = fminf(v, __shfl_xor(v, 8));
      runmin[m][r] = v;
    }
  if (lr == 0) {
#pragma unroll
    for (int m = 0; m < 8; ++m)
#pragma unroll
      for (int r = 0; r < 4; ++r) rowmin4[wc][m * 16 + g * 4 + r] = runmin[m][r];
  }
  __syncthreads();
  if (t < BM3) {
    const float v = fminf(fminf(rowmin4[0][t], rowmin4[1][t]),
                          fminf(rowmin4[2][t], rowmin4[3][t]));
    pmin[(row0 + t) * NCT3 + ct] = v;
  }
}

// ---- final: 8-way min + sqrt ----
__global__ __launch_bounds__(256) void final_min8(const float* __restrict__ esq,
                                                  const float* __restrict__ pmin,
                                                  float* __restrict__ out) {
  const int r = blockIdx.x * 256 + threadIdx.x;
  const float4* p = reinterpret_cast<const float4*>(pmin + (size_t)r * 8);
  float4 a = p[0], b = p[1];
  float m = fminf(fminf(fminf(a.x, a.y), fminf(a.z, a.w)),
                  fminf(fminf(b.x, b.y), fminf(b.z, b.w)));
  out[r] = sqrtf(fmaxf(esq[r] + m, 0.f));
}

// =================== round-1 fallback (proven) ===================
template <bool WS>
__global__ __launch_bounds__(256, 2) void fused_min(const float* __restrict__ embeds,
                                                    const float* __restrict__ centf,
                                                    const __bf16* __restrict__ cbf,
                                                    const float* __restrict__ csq,
                                                    float* __restrict__ out) {
  __shared__ __align__(16) char Ab[TM * 128];
  __shared__ __align__(16) char Bb[TN * 128];
  __shared__ float rowmin2[2][TM];
  __shared__ float sqrow[TM];
  __shared__ float colsq[TN];

  const int t = threadIdx.x;
  const int w = t >> 6;
  const int l = t & 63;
  const int wr = w >> 1, wc = w & 1;
  const int g = l >> 4, lr = l & 15;
  const long row0 = (long)blockIdx.x * TM;

  float runmin[4][4];
#pragma unroll
  for (int m = 0; m < 4; ++m)
#pragma unroll
    for (int r = 0; r < 4; ++r) runmin[m][r] = 3.0e38f;

  float sqpart[8];
#pragma unroll
  for (int c = 0; c < 8; ++c) sqpart[c] = 0.f;

  for (int nt = 0; nt < NT_TILES; ++nt) {
    const int col0 = nt * TN;
    f32x4 acc[4][4];
#pragma unroll
    for (int m = 0; m < 4; ++m)
#pragma unroll
      for (int n = 0; n < 4; ++n) acc[m][n] = (f32x4){0.f, 0.f, 0.f, 0.f};

    float cpart[8];
    if constexpr (!WS) {
#pragma unroll
      for (int c = 0; c < 8; ++c) cpart[c] = 0.f;
    }

    for (int kt = 0; kt < KT_STEPS; ++kt) {
      __syncthreads();
      if constexpr (WS) {
#pragma unroll
        for (int i = 0; i < 4; ++i) {
          const int s = (w * 4 + i) * 64 + l;
          const int col = s >> 3, sl = s & 7;
          const __bf16* src =
              cbf + (size_t)(col0 + col) * D_K + kt * BK + ((sl ^ (col & 7)) << 3);
          __builtin_amdgcn_global_load_lds(
              (const AS1 unsigned int*)(const void*)src,
              (AS3 unsigned int*)(void*)(Bb + (w * 4 + i) * 1024), 16, 0, 0);
        }
      } else {
#pragma unroll
        for (int c = 0; c < 8; ++c) {
          const int f = c * 256 + t;
          const int col = f >> 4, kq = f & 15;
          const float4 v = *reinterpret_cast<const float4*>(
              centf + (size_t)(col0 + col) * D_K + kt * BK + kq * 4);
          cpart[c] += v.x * v.x + v.y * v.y + v.z * v.z + v.w * v.w;
          bf16x4 o = {(__bf16)v.x, (__bf16)v.y, (__bf16)v.z, (__bf16)v.w};
          const int slot = kq >> 1;
          *reinterpret_cast<bf16x4*>(Bb + col * 128 + ((slot ^ (col & 7)) << 4) +
                                     (kq & 1) * 8) = o;
        }
      }
#pragma unroll
      for (int c = 0; c < 8; ++c) {
        const int f = c * 256 + t;
        const int row = f >> 4, kq = f & 15;
        const float4 v = *reinterpret_cast<const float4*>(
            embeds + (row0 + row) * (long)D_K + kt * BK + kq * 4);
        if (nt == 0) sqpart[c] += v.x * v.x + v.y * v.y + v.z * v.z + v.w * v.w;
        bf16x4 o = {(__bf16)v.x, (__bf16)v.y, (__bf16)v.z, (__bf16)v.w};
        const int slot = kq >> 1;
        *reinterpret_cast<bf16x4*>(Ab + row * 128 + ((slot ^ (row & 7)) << 4) +
                                   (kq & 1) * 8) = o;
      }
      __syncthreads();
#pragma unroll
      for (int ks = 0; ks < 2; ++ks) {
        bf16x8 af[4], bfr[4];
#pragma unroll
        for (int m = 0; m < 4; ++m) {
          const int row = wr * 64 + m * 16 + lr;
          const int slot = ks * 4 + g;
          af[m] = *reinterpret_cast<const bf16x8*>(Ab + row * 128 +
                                                   ((slot ^ (row & 7)) << 4));
        }
#pragma unroll
        for (int n = 0; n < 4; ++n) {
          const int col = wc * 64 + n * 16 + lr;
          const int slot = ks * 4 + g;
          bfr[n] = *reinterpret_cast<const bf16x8*>(Bb + col * 128 +
                                                    ((slot ^ (col & 7)) << 4));
        }
#pragma unroll
        for (int m = 0; m < 4; ++m)
#pragma unroll
          for (int n = 0; n < 4; ++n)
            acc[m][n] =
                __builtin_amdgcn_mfma_f32_16x16x32_bf16(af[m], bfr[n], acc[m][n], 0, 0, 0);
      }
    }

    if (nt == 0) {
#pragma unroll
      for (int c = 0; c < 8; ++c) {
        float ss = sqpart[c];
        ss += __shfl_xor(ss, 1);
        ss += __shfl_xor(ss, 2);
        ss += __shfl_xor(ss, 4);
        ss += __shfl_xor(ss, 8);
        if (lr == 0) sqrow[c * 16 + (w * 4 + g)] = ss;
      }
    }
    if constexpr (!WS) {
#pragma unroll
      for (int c = 0; c < 8; ++c) {
        float ss = cpart[c];
        ss += __shfl_xor(ss, 1);
        ss += __shfl_xor(ss, 2);
        ss += __shfl_xor(ss, 4);
        ss += __shfl_xor(ss, 8);
        if (lr == 0) colsq[c * 16 + (w * 4 + g)] = ss;
      }
      __syncthreads();
    }

#pragma unroll
    for (int n = 0; n < 4; ++n) {
      float cs;
      if constexpr (WS)
        cs = csq[col0 + wc * 64 + n * 16 + lr];
      else
        cs = colsq[wc * 64 + n * 16 + lr];
#pragma unroll
      for (int m = 0; m < 4; ++m)
#pragma unroll
        for (int r = 0; r < 4; ++r)
          runmin[m][r] = fminf(runmin[m][r], cs - 2.0f * acc[m][n][r]);
    }
  }

#pragma unroll
  for (int m = 0; m < 4; ++m)
#pragma unroll
    for (int r = 0; r < 4; ++r) {
      float v = runmin[m][r];
      v = fminf(v, __shfl_xor(v, 1));
      v = fminf(v, __shfl_xor(v, 2));
      v = fminf(v, __shfl_xor(v, 4));
      v = fminf(v, __shfl_xor(v, 8));
      runmin[m][r] = v;
    }
  if (lr == 0) {
#pragma unroll
    for (int m = 0; m < 4; ++m)
#pragma unroll
      for (int r = 0; r < 4; ++r)
        rowmin2[wc][wr * 64 + m * 16 + g * 4 + r] = runmin[m][r];
  }
  __syncthreads();
  if (t < TM) {
    const float v = fminf(rowmin2[0][t], rowmin2[1][t]);
    out[row0 + t] = sqrtf(fmaxf(sqrow[t] + v, 0.f));
  }
}

extern "C" void kernel_launch(void* const* d_in, const int* in_sizes, int n_in,
                              void* d_out, int out_size, void* d_ws, size_t ws_size,
                              hipStream_t stream) {
  const float* embeds = (const float*)d_in[0];
  const float* cent = (const float*)d_in[1];
  float* out = (float*)d_out;

  // ws layout for the fast path
  const size_t off_cbf = 0;
  const size_t off_csq = off_cbf + (size_t)M_CENT * D_K * 2;        // 4 MiB
  const size_t off_ebf = off_csq + (size_t)M_CENT * 4;              // +8 KiB
  const size_t off_esq = off_ebf + (size_t)N_ROWS * D_K * 2;        // +196 MiB
  const size_t off_pmin = off_esq + (size_t)N_ROWS * 4;             // +392 KiB
  const size_t need_full = off_pmin + (size_t)N_ROWS * NCT3 * 4;    // +3.1 MiB
  const size_t need_small = (size_t)M_CENT * D_K * 2 + (size_t)M_CENT * 4;

  if (ws_size >= need_full) {
    __bf16* cbf = (__bf16*)((char*)d_ws + off_cbf);
    float* csq = (float*)((char*)d_ws + off_csq);
    __bf16* ebf = (__bf16*)((char*)d_ws + off_ebf);
    float* esq = (float*)((char*)d_ws + off_esq);
    float* pmin = (float*)((char*)d_ws + off_pmin);
    rowsq_bf16<<<M_CENT, 256, 0, stream>>>(cent, cbf, csq);
    rowsq_bf16<<<N_ROWS, 256, 0, stream>>>(embeds, ebf, esq);
    gemm_min_w128<<<NBLK3, 256, 0, stream>>>(ebf, cbf, csq, pmin);
    final_min8<<<N_ROWS / 256, 256, 0, stream>>>(esq, pmin, out);
  } else if (ws_size >= need_small) {
    __bf16* cbf = (__bf16*)d_ws;
    float* csq = (float*)((char*)d_ws + (size_t)M_CENT * D_K * 2);
    rowsq_bf16<<<M_CENT, 256, 0, stream>>>(cent, cbf, csq);
    fused_min<true><<<N_ROWS / TM, 256, 0, stream>>>(embeds, cent, cbf, csq, out);
  } else {
    fused_min<false><<<N_ROWS / TM, 256, 0, stream>>>(embeds, cent, nullptr, nullptr, out);
  }
}

// Round 5
// 412.156 us; speedup vs baseline: 1.3158x; 1.3158x over previous
//
#include <hip/hip_runtime.h>
#include <hip/hip_bf16.h>

// CentroidsFlowAD: out[row] = sqrt(max(||e||^2 + min_col(||c||^2 - 2 e.c), 0))
// rows = 32*3136 = 100352, cols = 2048 centroids, K = 1024.
//
// Fast path (needs ~112 MiB ws), fp8 e4m3 cross-term (row norms exact fp32):
//   1. rowsq_fp8pack on centroids -> c8 (packed fp8) + csq
//   2. rowsq_fp8pack on embeds    -> e8 (packed fp8) + esq
//   3. gemm_min_fp8: 128x128 tile, BK=128, 4 waves (64x64), double-buffered
//      LDS 64 KiB -> 2 blocks/CU, counted vmcnt(8) (drains only at last
//      tile), 2 barriers per K-tile (16 total). Discipline (R3 lesson):
//      WAITVM -> barrier -> ds_read -> lgkm0 -> barrier -> stage-next+MFMA.
//      fp8 halves LDS bytes/MFMA vs bf16 (the 40-50% wall of R0/R2/R4).
//   4. final_min: 16-way min + sqrt
// fp8 K-packed row layout (128B per K-tile of 128): 16B slot s=ksp*4+g holds
// k = {32*(2ksp)+8g..+7 | 32*(2ksp+1)+8g..+7} -> lane (g,lr) b128 = both
// MFMA operands of a ksp pair. Slot swizzle s^(row&7) (full 8-spread).
// Fallback: round-1 fused kernel (proven, bf16).

typedef __bf16 bf16x8 __attribute__((ext_vector_type(8)));
typedef __bf16 bf16x4 __attribute__((ext_vector_type(4)));
typedef float f32x4 __attribute__((ext_vector_type(4)));
typedef long lx2 __attribute__((ext_vector_type(2)));

#define N_ROWS 100352
#define M_CENT 2048
#define D_K 1024

// fp8 fast-path geometry
#define BM4 128
#define BN4 128
#define BK4 128
#define NT4 (D_K / BK4)              // 8 K-tiles
#define NCT4 (M_CENT / BN4)          // 16 col tiles
#define NBLK4 ((N_ROWS / BM4) * NCT4)  // 12544
#define BPX4 (NBLK4 / 8)             // 1568 per XCD

// fallback geometry (round-1, unchanged)
#define TM 128
#define TN 128
#define BK 64
#define NT_TILES (M_CENT / TN)  // 16
#define KT_STEPS (D_K / BK)     // 16

#define AS1 __attribute__((address_space(1)))
#define AS3 __attribute__((address_space(3)))

#define WAITVM(N) asm volatile("s_waitcnt vmcnt(" #N ")" ::: "memory")
#define LGKM0 asm volatile("s_waitcnt lgkmcnt(0)" ::: "memory")
#define FENCE asm volatile("" ::: "memory")

// ---- prep: fp32 [rows][1024] -> packed fp8 row + per-row squared norm ----
// Packed byte position within row: seg(=K-tile)*128 + (ksp*4+g)*16 + h*8 + j
// where k = 32*(2*ksp+h) + 8*g + j.
__global__ __launch_bounds__(256) void rowsq_fp8pack(const float* __restrict__ src,
                                                     unsigned char* __restrict__ dst,
                                                     float* __restrict__ sq) {
  const int m = blockIdx.x;   // row
  const int t = threadIdx.x;  // 256 threads * 4 floats = 1024
  const float4 v = *reinterpret_cast<const float4*>(src + (size_t)m * D_K + t * 4);
  int pk = __builtin_amdgcn_cvt_pk_fp8_f32(v.x, v.y, 0, false);
  pk = __builtin_amdgcn_cvt_pk_fp8_f32(v.z, v.w, pk, true);
  const int k = t * 4;
  const int seg = k >> 7;
  const int ksi = (k >> 5) & 3;
  const int g = (k >> 3) & 3;
  const int j = k & 7;  // 0 or 4
  const int p = seg * 128 + (((ksi >> 1) * 4 + g) << 4) + (ksi & 1) * 8 + j;
  *reinterpret_cast<unsigned int*>(dst + (size_t)m * D_K + p) = (unsigned int)pk;
  float ss = v.x * v.x + v.y * v.y + v.z * v.z + v.w * v.w;
  ss += __shfl_xor(ss, 1);
  ss += __shfl_xor(ss, 2);
  ss += __shfl_xor(ss, 4);
  ss += __shfl_xor(ss, 8);
  ss += __shfl_xor(ss, 16);
  ss += __shfl_xor(ss, 32);
  __shared__ float ws4[4];
  const int w = t >> 6, l = t & 63;
  if (l == 0) ws4[w] = ss;
  __syncthreads();
  if (t == 0) sq[m] = ws4[0] + ws4[1] + ws4[2] + ws4[3];
}

// ---- fast path: fp8 128x128 tile, BK=128, dbuf, counted vmcnt ----
// LDS buffer: A[128 rows][128 B] 16K | B[128][128 B] 16K; 2 buffers = 64 KB.
// Staging: 8 global_load_lds w=16 per thread per K-tile (A:4, B:4), linear
// dest, inverse-swizzled packed-global source.
// K-tile kt (buf = kt&1):
//   stage(kt+1 -> buf^1)   [kt<7]  -- overwrites buf read at kt-1; safe:
//                                     issued after B2(kt-1) which ordered
//                                     after ALL waves' kt-1 reads (lgkm0).
//   WAITVM(8)                      -- my stage(kt) landed (kt+1 in flight)
//   s_barrier (B1)                 -- ALL waves' stage(kt) landed
//   16 ds_read_b128 from buf
//   lgkm0; s_barrier (B2)          -- all reads done
//   64 MFMA fp8 (setprio)
__global__ __launch_bounds__(256, 2) void gemm_min_fp8(const unsigned char* __restrict__ e8,
                                                       const unsigned char* __restrict__ c8,
                                                       const float* __restrict__ csq,
                                                       float* __restrict__ pmin) {
  __shared__ __align__(16) char lds[2 * 32768];
  __shared__ float rowmin2[2][BM4];

  const int t = threadIdx.x;
  const int w = t >> 6;
  const int l = t & 63;
  const int wr = w >> 1, wc = w & 1;  // 2x2 wave grid, 64x64 tiles
  const int g = l >> 4, lr = l & 15;

  // XCD swizzle: XCD k owns swz in [1568k,1568k+1568) = rp in [98k,98k+98)
  // x all 16 ct. c8 (2 MB) L2-resident; A panel (128 KB) reused 16x L2-hot.
  const int b = blockIdx.x;
  const int swz = (b & 7) * BPX4 + (b >> 3);
  const int rp = swz >> 4, ct = swz & 15;
  const long row0 = (long)rp * BM4;
  const int col0 = ct * BN4;

  // staging: dest linear d = i*4096 + t*16 -> row = i*32 + (t>>3), slot = t&7
  // (row&7 i-invariant). source = row*1024 + kt*128 + ((slot^(row&7))<<4).
  const int trow = t >> 3, tsl = t & 7;
  const int ssw = (tsl ^ (trow & 7)) << 4;
  const unsigned char* srcA0 = e8 + (row0 + trow) * (size_t)D_K + ssw;
  const unsigned char* srcB0 = c8 + (size_t)(col0 + trow) * D_K + ssw;
  const int dst0 = t * 16;

  f32x4 acc[4][4];
#pragma unroll
  for (int m = 0; m < 4; ++m)
#pragma unroll
    for (int n = 0; n < 4; ++n) acc[m][n] = (f32x4){0.f, 0.f, 0.f, 0.f};

  // loop-invariant swizzled read offsets: frag (m|n, ksp) slot = ksp*4+g
  int offA[4][2], offB[4][2];
#pragma unroll
  for (int m = 0; m < 4; ++m) {
    const int row = wr * 64 + m * 16 + lr;
#pragma unroll
    for (int ksp = 0; ksp < 2; ++ksp)
      offA[m][ksp] = row * 128 + (((ksp * 4 + g) ^ (row & 7)) << 4);
  }
#pragma unroll
  for (int n = 0; n < 4; ++n) {
    const int col = wc * 64 + n * 16 + lr;
#pragma unroll
    for (int ksp = 0; ksp < 2; ++ksp)
      offB[n][ksp] = 16384 + col * 128 + (((ksp * 4 + g) ^ (col & 7)) << 4);
  }

  lx2 af[4][2], bfr[4][2];

  auto stage = [&](int kt, int buf) {
    char* base = lds + buf * 32768;
    const size_t ko = (size_t)kt * BK4;
#pragma unroll
    for (int i = 0; i < 4; ++i)
      __builtin_amdgcn_global_load_lds(
          (const AS1 unsigned int*)(const void*)(srcA0 + (size_t)i * 32 * D_K + ko),
          (AS3 unsigned int*)(void*)(base + i * 4096 + dst0), 16, 0, 0);
#pragma unroll
    for (int i = 0; i < 4; ++i)
      __builtin_amdgcn_global_load_lds(
          (const AS1 unsigned int*)(const void*)(srcB0 + (size_t)i * 32 * D_K + ko),
          (AS3 unsigned int*)(void*)(base + 16384 + i * 4096 + dst0), 16, 0, 0);
  };

  auto readfrags = [&](int buf) {
    const char* base = lds + buf * 32768;
#pragma unroll
    for (int m = 0; m < 4; ++m)
#pragma unroll
      for (int ksp = 0; ksp < 2; ++ksp)
        af[m][ksp] = *reinterpret_cast<const lx2*>(base + offA[m][ksp]);
#pragma unroll
    for (int n = 0; n < 4; ++n)
#pragma unroll
      for (int ksp = 0; ksp < 2; ++ksp)
        bfr[n][ksp] = *reinterpret_cast<const lx2*>(base + offB[n][ksp]);
  };

  auto domfma = [&]() {
    __builtin_amdgcn_s_setprio(1);
#pragma unroll
    for (int ksp = 0; ksp < 2; ++ksp)
#pragma unroll
      for (int m = 0; m < 4; ++m)
#pragma unroll
        for (int n = 0; n < 4; ++n) {
          acc[m][n] = __builtin_amdgcn_mfma_f32_16x16x32_fp8_fp8(
              af[m][ksp][0], bfr[n][ksp][0], acc[m][n], 0, 0, 0);
          acc[m][n] = __builtin_amdgcn_mfma_f32_16x16x32_fp8_fp8(
              af[m][ksp][1], bfr[n][ksp][1], acc[m][n], 0, 0, 0);
        }
    __builtin_amdgcn_s_setprio(0);
  };

  stage(0, 0);
#pragma unroll
  for (int kt = 0; kt < NT4; ++kt) {
    const int buf = kt & 1;
    if (kt < NT4 - 1) {
      stage(kt + 1, buf ^ 1);
      WAITVM(8);
    } else {
      WAITVM(0);
    }
    FENCE;
    __builtin_amdgcn_s_barrier();  // B1: tile kt fully landed (all waves)
    FENCE;
    readfrags(buf);
    LGKM0;
    FENCE;
    __builtin_amdgcn_s_barrier();  // B2: all reads done -> buf reusable
    FENCE;
    domfma();
  }

  // --- partial min over this block's 128 cols: val = ||c||^2 - 2*dot ---
  float runmin[4][4];
#pragma unroll
  for (int m = 0; m < 4; ++m)
#pragma unroll
    for (int r = 0; r < 4; ++r) runmin[m][r] = 3.0e38f;
#pragma unroll
  for (int n = 0; n < 4; ++n) {
    const float cs = csq[col0 + wc * 64 + n * 16 + lr];
#pragma unroll
    for (int m = 0; m < 4; ++m)
#pragma unroll
      for (int r = 0; r < 4; ++r)
        runmin[m][r] = fminf(runmin[m][r], cs - 2.0f * acc[m][n][r]);
  }
#pragma unroll
  for (int m = 0; m < 4; ++m)
#pragma unroll
    for (int r = 0; r < 4; ++r) {
      float v = runmin[m][r];
      v = fminf(v, __shfl_xor(v, 1));
      v = fminf(v, __shfl_xor(v, 2));
      v = fminf(v, __shfl_xor(v, 4));
      v = fminf(v, __shfl_xor(v, 8));
      runmin[m][r] = v;
    }
  if (lr == 0) {
#pragma unroll
    for (int m = 0; m < 4; ++m)
#pragma unroll
      for (int r = 0; r < 4; ++r)
        rowmin2[wc][wr * 64 + m * 16 + g * 4 + r] = runmin[m][r];
  }
  __syncthreads();
  if (t < BM4) {
    pmin[(row0 + t) * NCT4 + ct] = fminf(rowmin2[0][t], rowmin2[1][t]);
  }
}

// ---- final: 16-way min + sqrt ----
__global__ __launch_bounds__(256) void final_min(const float* __restrict__ esq,
                                                 const float* __restrict__ pmin,
                                                 float* __restrict__ out) {
  const int r = blockIdx.x * 256 + threadIdx.x;
  const float4* p = reinterpret_cast<const float4*>(pmin + (size_t)r * 16);
  float4 a = p[0], b = p[1], c = p[2], d = p[3];
  float m = fminf(fminf(fminf(a.x, a.y), fminf(a.z, a.w)),
                  fminf(fminf(b.x, b.y), fminf(b.z, b.w)));
  m = fminf(m, fminf(fminf(fminf(c.x, c.y), fminf(c.z, c.w)),
                     fminf(fminf(d.x, d.y), fminf(d.z, d.w))));
  out[r] = sqrtf(fmaxf(esq[r] + m, 0.f));
}

// ---- bf16 prep (fallback path) ----
__global__ __launch_bounds__(256) void rowsq_bf16(const float* __restrict__ src,
                                                  __bf16* __restrict__ dst,
                                                  float* __restrict__ sq) {
  const int m = blockIdx.x;
  const int t = threadIdx.x;
  const float4 v = *reinterpret_cast<const float4*>(src + (size_t)m * D_K + t * 4);
  bf16x4 o = {(__bf16)v.x, (__bf16)v.y, (__bf16)v.z, (__bf16)v.w};
  *reinterpret_cast<bf16x4*>(dst + (size_t)m * D_K + t * 4) = o;
  float ss = v.x * v.x + v.y * v.y + v.z * v.z + v.w * v.w;
  ss += __shfl_xor(ss, 1);
  ss += __shfl_xor(ss, 2);
  ss += __shfl_xor(ss, 4);
  ss += __shfl_xor(ss, 8);
  ss += __shfl_xor(ss, 16);
  ss += __shfl_xor(ss, 32);
  __shared__ float ws4[4];
  const int w = t >> 6, l = t & 63;
  if (l == 0) ws4[w] = ss;
  __syncthreads();
  if (t == 0) sq[m] = ws4[0] + ws4[1] + ws4[2] + ws4[3];
}

// =================== round-1 fallback (proven) ===================
template <bool WS>
__global__ __launch_bounds__(256, 2) void fused_min(const float* __restrict__ embeds,
                                                    const float* __restrict__ centf,
                                                    const __bf16* __restrict__ cbf,
                                                    const float* __restrict__ csq,
                                                    float* __restrict__ out) {
  __shared__ __align__(16) char Ab[TM * 128];
  __shared__ __align__(16) char Bb[TN * 128];
  __shared__ float rowmin2[2][TM];
  __shared__ float sqrow[TM];
  __shared__ float colsq[TN];

  const int t = threadIdx.x;
  const int w = t >> 6;
  const int l = t & 63;
  const int wr = w >> 1, wc = w & 1;
  const int g = l >> 4, lr = l & 15;
  const long row0 = (long)blockIdx.x * TM;

  float runmin[4][4];
#pragma unroll
  for (int m = 0; m < 4; ++m)
#pragma unroll
    for (int r = 0; r < 4; ++r) runmin[m][r] = 3.0e38f;

  float sqpart[8];
#pragma unroll
  for (int c = 0; c < 8; ++c) sqpart[c] = 0.f;

  for (int nt = 0; nt < NT_TILES; ++nt) {
    const int col0 = nt * TN;
    f32x4 acc[4][4];
#pragma unroll
    for (int m = 0; m < 4; ++m)
#pragma unroll
      for (int n = 0; n < 4; ++n) acc[m][n] = (f32x4){0.f, 0.f, 0.f, 0.f};

    float cpart[8];
    if constexpr (!WS) {
#pragma unroll
      for (int c = 0; c < 8; ++c) cpart[c] = 0.f;
    }

    for (int kt = 0; kt < KT_STEPS; ++kt) {
      __syncthreads();
      if constexpr (WS) {
#pragma unroll
        for (int i = 0; i < 4; ++i) {
          const int s = (w * 4 + i) * 64 + l;
          const int col = s >> 3, sl = s & 7;
          const __bf16* src =
              cbf + (size_t)(col0 + col) * D_K + kt * BK + ((sl ^ (col & 7)) << 3);
          __builtin_amdgcn_global_load_lds(
              (const AS1 unsigned int*)(const void*)src,
              (AS3 unsigned int*)(void*)(Bb + (w * 4 + i) * 1024), 16, 0, 0);
        }
      } else {
#pragma unroll
        for (int c = 0; c < 8; ++c) {
          const int f = c * 256 + t;
          const int col = f >> 4, kq = f & 15;
          const float4 v = *reinterpret_cast<const float4*>(
              centf + (size_t)(col0 + col) * D_K + kt * BK + kq * 4);
          cpart[c] += v.x * v.x + v.y * v.y + v.z * v.z + v.w * v.w;
          bf16x4 o = {(__bf16)v.x, (__bf16)v.y, (__bf16)v.z, (__bf16)v.w};
          const int slot = kq >> 1;
          *reinterpret_cast<bf16x4*>(Bb + col * 128 + ((slot ^ (col & 7)) << 4) +
                                     (kq & 1) * 8) = o;
        }
      }
#pragma unroll
      for (int c = 0; c < 8; ++c) {
        const int f = c * 256 + t;
        const int row = f >> 4, kq = f & 15;
        const float4 v = *reinterpret_cast<const float4*>(
            embeds + (row0 + row) * (long)D_K + kt * BK + kq * 4);
        if (nt == 0) sqpart[c] += v.x * v.x + v.y * v.y + v.z * v.z + v.w * v.w;
        bf16x4 o = {(__bf16)v.x, (__bf16)v.y, (__bf16)v.z, (__bf16)v.w};
        const int slot = kq >> 1;
        *reinterpret_cast<bf16x4*>(Ab + row * 128 + ((slot ^ (row & 7)) << 4) +
                                   (kq & 1) * 8) = o;
      }
      __syncthreads();
#pragma unroll
      for (int ks = 0; ks < 2; ++ks) {
        bf16x8 af[4], bfr[4];
#pragma unroll
        for (int m = 0; m < 4; ++m) {
          const int row = wr * 64 + m * 16 + lr;
          const int slot = ks * 4 + g;
          af[m] = *reinterpret_cast<const bf16x8*>(Ab + row * 128 +
                                                   ((slot ^ (row & 7)) << 4));
        }
#pragma unroll
        for (int n = 0; n < 4; ++n) {
          const int col = wc * 64 + n * 16 + lr;
          const int slot = ks * 4 + g;
          bfr[n] = *reinterpret_cast<const bf16x8*>(Bb + col * 128 +
                                                    ((slot ^ (col & 7)) << 4));
        }
#pragma unroll
        for (int m = 0; m < 4; ++m)
#pragma unroll
          for (int n = 0; n < 4; ++n)
            acc[m][n] =
                __builtin_amdgcn_mfma_f32_16x16x32_bf16(af[m], bfr[n], acc[m][n], 0, 0, 0);
      }
    }

    if (nt == 0) {
#pragma unroll
      for (int c = 0; c < 8; ++c) {
        float ss = sqpart[c];
        ss += __shfl_xor(ss, 1);
        ss += __shfl_xor(ss, 2);
        ss += __shfl_xor(ss, 4);
        ss += __shfl_xor(ss, 8);
        if (lr == 0) sqrow[c * 16 + (w * 4 + g)] = ss;
      }
    }
    if constexpr (!WS) {
#pragma unroll
      for (int c = 0; c < 8; ++c) {
        float ss = cpart[c];
        ss += __shfl_xor(ss, 1);
        ss += __shfl_xor(ss, 2);
        ss += __shfl_xor(ss, 4);
        ss += __shfl_xor(ss, 8);
        if (lr == 0) colsq[c * 16 + (w * 4 + g)] = ss;
      }
      __syncthreads();
    }

#pragma unroll
    for (int n = 0; n < 4; ++n) {
      float cs;
      if constexpr (WS)
        cs = csq[col0 + wc * 64 + n * 16 + lr];
      else
        cs = colsq[wc * 64 + n * 16 + lr];
#pragma unroll
      for (int m = 0; m < 4; ++m)
#pragma unroll
        for (int r = 0; r < 4; ++r)
          runmin[m][r] = fminf(runmin[m][r], cs - 2.0f * acc[m][n][r]);
    }
  }

#pragma unroll
  for (int m = 0; m < 4; ++m)
#pragma unroll
    for (int r = 0; r < 4; ++r) {
      float v = runmin[m][r];
      v = fminf(v, __shfl_xor(v, 1));
      v = fminf(v, __shfl_xor(v, 2));
      v = fminf(v, __shfl_xor(v, 4));
      v = fminf(v, __shfl_xor(v, 8));
      runmin[m][r] = v;
    }
  if (lr == 0) {
#pragma unroll
    for (int m = 0; m < 4; ++m)
#pragma unroll
      for (int r = 0; r < 4; ++r)
        rowmin2[wc][wr * 64 + m * 16 + g * 4 + r] = runmin[m][r];
  }
  __syncthreads();
  if (t < TM) {
    const float v = fminf(rowmin2[0][t], rowmin2[1][t]);
    out[row0 + t] = sqrtf(fmaxf(sqrow[t] + v, 0.f));
  }
}

extern "C" void kernel_launch(void* const* d_in, const int* in_sizes, int n_in,
                              void* d_out, int out_size, void* d_ws, size_t ws_size,
                              hipStream_t stream) {
  const float* embeds = (const float*)d_in[0];
  const float* cent = (const float*)d_in[1];
  float* out = (float*)d_out;

  // ws layout for the fp8 fast path (~112 MiB)
  const size_t off_c8 = 0;
  const size_t off_csq = off_c8 + (size_t)M_CENT * D_K;             // 2 MiB
  const size_t off_e8 = off_csq + (size_t)M_CENT * 4;               // +8 KiB
  const size_t off_esq = off_e8 + (size_t)N_ROWS * D_K;             // +98 MiB
  const size_t off_pmin = off_esq + (size_t)N_ROWS * 4;             // +392 KiB
  const size_t need_full = off_pmin + (size_t)N_ROWS * NCT4 * 4;    // +6.1 MiB
  const size_t need_small = (size_t)M_CENT * D_K * 2 + (size_t)M_CENT * 4;

  if (ws_size >= need_full) {
    unsigned char* c8 = (unsigned char*)d_ws + off_c8;
    float* csq = (float*)((char*)d_ws + off_csq);
    unsigned char* e8 = (unsigned char*)d_ws + off_e8;
    float* esq = (float*)((char*)d_ws + off_esq);
    float* pmin = (float*)((char*)d_ws + off_pmin);
    rowsq_fp8pack<<<M_CENT, 256, 0, stream>>>(cent, c8, csq);
    rowsq_fp8pack<<<N_ROWS, 256, 0, stream>>>(embeds, e8, esq);
    gemm_min_fp8<<<NBLK4, 256, 0, stream>>>(e8, c8, csq, pmin);
    final_min<<<N_ROWS / 256, 256, 0, stream>>>(esq, pmin, out);
  } else if (ws_size >= need_small) {
    __bf16* cbf = (__bf16*)d_ws;
    float* csq = (float*)((char*)d_ws + (size_t)M_CENT * D_K * 2);
    rowsq_bf16<<<M_CENT, 256, 0, stream>>>(cent, cbf, csq);
    fused_min<true><<<N_ROWS / TM, 256, 0, stream>>>(embeds, cent, cbf, csq, out);
  } else {
    fused_min<false><<<N_ROWS / TM, 256, 0, stream>>>(embeds, cent, nullptr, nullptr, out);
  }
}